// Round 1
// 193.271 us; speedup vs baseline: 1.0305x; 1.0305x over previous
//
#include <hip/hip_runtime.h>
#include <stdint.h>

#define N_NODES 50000
#define N_EDGES 800000
#define H_DIM 128
#define N_REL 40
#define N_BASES 4
#define N_RANGES 196         // node ranges of 256 (dst >> 8)
#define EP_BLOCKS 200        // edge chunks of 4000
#define EDGES_PER_BLK 4000
#define STAGE_CAP 5120       // LDS staging capacity for bucket_sort

typedef __attribute__((ext_vector_type(8))) short bf16x8;
typedef __attribute__((ext_vector_type(4))) float f32x4;

// round-to-nearest-even f32 -> bf16 bits
__device__ __forceinline__ unsigned short f2bf(float f) {
    unsigned int u = __float_as_uint(f);
    unsigned int r = u + 0x7fffu + ((u >> 16) & 1u);
    return (unsigned short)(r >> 16);
}

// ---------------------------------------------------------------------------
// K0 "prep" (fused): blocks 0..3124   -> cast h into A (bf16, stride 128)
//                    blocks 3125..3129 -> repack weights into frag-major wt3
//                    blocks 3130..3329 -> edge pack (pkd) + per-(bucket,block)
//                                         histogram (LDS only, no dev atomics)
// pkd[e] = { src | etype<<20 , dst | nbf<<17 }  (nbf = bf16 of norm >= 0)
__global__ __launch_bounds__(256) void prep_kernel(
        const float* __restrict__ h,
        const float* __restrict__ basis_w, const float* __restrict__ loop_w,
        const int* __restrict__ src, const int* __restrict__ dst,
        const int* __restrict__ etype, const float* __restrict__ norm,
        unsigned short* __restrict__ A, unsigned short* __restrict__ wt3,
        uint2* __restrict__ pkd, int* __restrict__ gcnt) {
    int bid = blockIdx.x;
    if (bid < 3125) {
        int t = bid * 256 + threadIdx.x;        // [0, 800000)
        int row = t >> 4;
        int cb = (t & 15) * 8;
        const float* p = h + (size_t)row * 128 + cb;
        float4 a0 = ((const float4*)p)[0];
        float4 a1 = ((const float4*)p)[1];
        bf16x8 o;
        o[0] = (short)f2bf(a0.x); o[1] = (short)f2bf(a0.y);
        o[2] = (short)f2bf(a0.z); o[3] = (short)f2bf(a0.w);
        o[4] = (short)f2bf(a1.x); o[5] = (short)f2bf(a1.y);
        o[6] = (short)f2bf(a1.z); o[7] = (short)f2bf(a1.w);
        *(bf16x8*)(A + (size_t)row * H_DIM + cb) = o;
    } else if (bid < 3130) {
        int mat = bid - 3125;                   // 0..3 basis, 4 loop
        const float* srcm = (mat < 4) ? (basis_w + mat * 16384) : loop_w;
        int koff = (mat < 4) ? (128 + mat * 128) : 0;
        int t = threadIdx.x;
#pragma unroll
        for (int i = 0; i < 16; ++i) {
            int f = t + i * 256;                // [0,4096) float4 index
            int k = f >> 5;
            int j4 = (f & 31) * 4;
            float4 v = ((const float4*)srcm)[f];
            int kg = koff + k;
            int ks = kg >> 5;
            int quad = (kg >> 3) & 3;
            int jj = kg & 7;
            float vv[4] = {v.x, v.y, v.z, v.w};
#pragma unroll
            for (int d = 0; d < 4; ++d) {
                int j = j4 + d;
                int cg = j >> 4;
                int n16 = j & 15;
                wt3[(size_t)((ks * 8 + cg) * 64 + quad * 16 + n16) * 8 + jj] =
                    f2bf(vv[d]);
            }
        }
    } else {
        __shared__ int lhist[N_RANGES];
        int blk = bid - 3130;                   // 0..199
        int t = threadIdx.x;
        if (t < N_RANGES) lhist[t] = 0;
        __syncthreads();
        int e0 = blk * EDGES_PER_BLK;
        for (int i = t; i < EDGES_PER_BLK; i += 256) {
            int e = e0 + i;
            int d = dst[e];
            unsigned int nbf = f2bf(norm[e]);   // <= 0x7FFF (norm >= 0)
            pkd[e] = make_uint2((unsigned)src[e] | ((unsigned)etype[e] << 20),
                                (unsigned)d | (nbf << 17));
            atomicAdd(&lhist[d >> 8], 1);
        }
        __syncthreads();
        if (t < N_RANGES) gcnt[t * EP_BLOCKS + blk] = lhist[t];
    }
}

// K1: parallel per-bucket row scan. Block r: LDS-scan gcnt[r][0..199] ->
// RELATIVE blkbase (bucket base added later in-block) + bucket total btot[r].
__global__ __launch_bounds__(256) void bucket_scan_a(
        const int* __restrict__ gcnt, int* __restrict__ blkbase,
        int* __restrict__ btot) {
    __shared__ int wsum[4];
    int r = blockIdx.x;
    int t = threadIdx.x, lane = t & 63, w = t >> 6;
    int x = (t < EP_BLOCKS) ? gcnt[r * EP_BLOCKS + t] : 0;
    int v = x;
#pragma unroll
    for (int d = 1; d < 64; d <<= 1) {
        int y = __shfl_up(v, d);
        if (lane >= d) v += y;
    }
    if (lane == 63) wsum[w] = v;
    __syncthreads();
    int wpre = 0;
    if (w > 0) wpre += wsum[0];
    if (w > 1) wpre += wsum[1];
    if (w > 2) wpre += wsum[2];
    if (t < EP_BLOCKS) blkbase[r * EP_BLOCKS + t] = wpre + v - x;
    if (t == 255) btot[r] = wpre + v;
}

// K2: binscatter. Block b places its 4000 edges into bucket-grouped order.
// Bucket bases recomputed in-block via a 196-wide scan of btot (scan_b fused
// away). Each (block,bucket) chunk (~20 edges) is contiguous -> ~1x write amp.
__global__ __launch_bounds__(256) void binscatter(
        const uint2* __restrict__ pkd, const int* __restrict__ blkbase,
        const int* __restrict__ btot, uint2* __restrict__ bucketed) {
    __shared__ int lcur[N_RANGES];
    __shared__ int wsum[4];
    int t = threadIdx.x, lane = t & 63, w = t >> 6;
    int x = (t < N_RANGES) ? btot[t] : 0;
    int v = x;
#pragma unroll
    for (int d = 1; d < 64; d <<= 1) {
        int y = __shfl_up(v, d);
        if (lane >= d) v += y;
    }
    if (lane == 63) wsum[w] = v;
    __syncthreads();
    int wpre = 0;
    if (w > 0) wpre += wsum[0];
    if (w > 1) wpre += wsum[1];
    if (w > 2) wpre += wsum[2];
    if (t < N_RANGES)
        lcur[t] = (wpre + v - x) + blkbase[t * EP_BLOCKS + blockIdx.x];
    __syncthreads();
    int e0 = blockIdx.x * EDGES_PER_BLK;
    for (int i = t; i < EDGES_PER_BLK; i += 256) {
        uint2 p = pkd[e0 + i];
        int r = (p.y & 0x1FFFF) >> 8;
        int pos = atomicAdd(&lcur[r], 1);
        bucketed[pos] = p;
    }
}

// K3: bucket_sort. One block per bucket. Bucket base recomputed in-block.
// Pass 1: LDS per-dst histogram -> 256-wide scan -> per-dst offsets (offs[]
// written coalesced). Pass 2: place edges into LDS stage by exact sorted
// position, stream out coalesced. Single-writer output region.
__global__ __launch_bounds__(256) void bucket_sort(
        const int* __restrict__ btot, const uint2* __restrict__ bucketed,
        uint2* __restrict__ sorted_pe, int* __restrict__ offs) {
    __shared__ int hist[256];
    __shared__ int cur[256];
    __shared__ int wsum[4];
    __shared__ int sbeg;
    __shared__ uint2 stage[STAGE_CAP];
    int r = blockIdx.x;
    int t = threadIdx.x, lane = t & 63, w = t >> 6;
    // recompute begin = exclusive prefix of btot at r
    int x = (t < N_RANGES) ? btot[t] : 0;
    int v = x;
#pragma unroll
    for (int d = 1; d < 64; d <<= 1) {
        int y = __shfl_up(v, d);
        if (lane >= d) v += y;
    }
    if (lane == 63) wsum[w] = v;
    hist[t] = 0;
    __syncthreads();
    int wpre = 0;
    if (w > 0) wpre += wsum[0];
    if (w > 1) wpre += wsum[1];
    if (w > 2) wpre += wsum[2];
    if (t == r) sbeg = wpre + v - x;
    __syncthreads();
    int begin = sbeg;
    int end = begin + btot[r];
    int n = end - begin;
    for (int i = begin + t; i < end; i += 256)
        atomicAdd(&hist[bucketed[i].y & 255], 1);
    __syncthreads();
    int x2 = hist[t];
    int v2 = x2;
#pragma unroll
    for (int d = 1; d < 64; d <<= 1) {
        int y = __shfl_up(v2, d);
        if (lane >= d) v2 += y;
    }
    if (lane == 63) wsum[w] = v2;
    __syncthreads();
    int wpre2 = 0;
    if (w > 0) wpre2 += wsum[0];
    if (w > 1) wpre2 += wsum[1];
    if (w > 2) wpre2 += wsum[2];
    int excl_rel = wpre2 + v2 - x2;             // position within the region
    int node = r * 256 + t;
    if (node < N_NODES) offs[node] = begin + excl_rel;
    if (r == N_RANGES - 1 && t == 0) offs[N_NODES] = N_EDGES;
    cur[t] = excl_rel;
    __syncthreads();
    if (n <= STAGE_CAP) {
        for (int i = begin + t; i < end; i += 256) {
            uint2 p = bucketed[i];
            int pos = atomicAdd(&cur[p.y & 255], 1);
            stage[pos] = make_uint2(p.x, (p.y >> 17) << 16);
        }
        __syncthreads();
        for (int i = t; i < n; i += 256)
            sorted_pe[begin + i] = stage[i];
    } else {                                    // pathological fallback
        for (int i = begin + t; i < end; i += 256) {
            uint2 p = bucketed[i];
            int pos = atomicAdd(&cur[p.y & 255], 1);
            sorted_pe[begin + pos] = make_uint2(p.x, (p.y >> 17) << 16);
        }
    }
}

// K4 (fused aggregate + GEMM): block = 32 nodes.
// Phase 1: wave w aggregates nodes [32*blk + 8w, +8), one node at a time
//   (edge metadata wave-uniform -> scalar loads; gathers are 256B rows of
//   bf16 hbf, 8 outstanding). The per-node 512-wide f32 S lives in 8 VGPRs;
//   it is converted to bf16 and written to an LDS tile [32][640] together
//   with the node's own hbf row. Rows XOR-swizzled (byte ^= (row&7)<<4) so
//   the MFMA-phase ds_read_b128 at 1280B row stride is bank-uniform.
// Phase 2: 32x128x640 bf16 MFMA tile straight out of LDS (wave = 32 cols,
//   acc[2][2]); B from wt3 (frag-major, L2-resident); bias+relu epilogue.
// Eliminates the 51.2MB S HBM write + 64MB A re-read of the old split.
__global__ __launch_bounds__(256) void agg_gemm(
        const int* __restrict__ offs, const uint2* __restrict__ sorted_pe,
        const float* __restrict__ w_comp,
        const unsigned short* __restrict__ Ab,
        const unsigned short* __restrict__ wt3,
        const float* __restrict__ bias, float* __restrict__ out) {
    __shared__ __align__(16) unsigned short S[32 * 640];   // 40 KB
    int wv = threadIdx.x >> 6;
    int lane = threadIdx.x & 63;
    int nbase = blockIdx.x * 32;
    const unsigned int* Au = (const unsigned int*)Ab;

    for (int q = 0; q < 8; ++q) {
        int row = (wv << 3) + q;
        int v = __builtin_amdgcn_readfirstlane(nbase + row);
        float a0l = 0.f, a0h = 0.f, a1l = 0.f, a1h = 0.f;
        float a2l = 0.f, a2h = 0.f, a3l = 0.f, a3h = 0.f;
        unsigned int hb = 0u;
        if (v < N_NODES) {
            hb = Au[(size_t)v * 64 + lane];     // own hbf row (cols 2l,2l+1)
            int begin = offs[v];
            int end = offs[v + 1];
            int j = begin;
            for (; j + 8 <= end; j += 8) {
                uint2 p[8];
                unsigned int u[8];
#pragma unroll
                for (int k = 0; k < 8; ++k) p[k] = sorted_pe[j + k];
#pragma unroll
                for (int k = 0; k < 8; ++k)
                    u[k] = Au[(size_t)(p[k].x & 0xFFFFF) * 64 + lane];
#pragma unroll
                for (int k = 0; k < 8; ++k) {
                    float4 wc = ((const float4*)w_comp)[p[k].x >> 20];
                    float nm = __uint_as_float(p[k].y);
                    float lo = __uint_as_float(u[k] << 16);
                    float hi = __uint_as_float(u[k] & 0xffff0000u);
                    a0l += (wc.x * nm) * lo; a0h += (wc.x * nm) * hi;
                    a1l += (wc.y * nm) * lo; a1h += (wc.y * nm) * hi;
                    a2l += (wc.z * nm) * lo; a2h += (wc.z * nm) * hi;
                    a3l += (wc.w * nm) * lo; a3h += (wc.w * nm) * hi;
                }
            }
            for (; j < end; ++j) {
                uint2 p = sorted_pe[j];
                float4 wc = ((const float4*)w_comp)[p.x >> 20];
                float nm = __uint_as_float(p.y);
                unsigned int u = Au[(size_t)(p.x & 0xFFFFF) * 64 + lane];
                float lo = __uint_as_float(u << 16);
                float hi = __uint_as_float(u & 0xffff0000u);
                a0l += (wc.x * nm) * lo; a0h += (wc.x * nm) * hi;
                a1l += (wc.y * nm) * lo; a1h += (wc.y * nm) * hi;
                a2l += (wc.z * nm) * lo; a2h += (wc.z * nm) * hi;
                a3l += (wc.w * nm) * lo; a3h += (wc.w * nm) * hi;
            }
        }
        // stage row into LDS: [hbf(256B) | S0 | S1 | S2 | S3], swizzled
        char* rp = (char*)S + row * 1280;
        int swz = (row & 7) << 4;
        *(unsigned int*)(rp + ((lane * 4) ^ swz)) = hb;
        *(unsigned int*)(rp + ((256 + lane * 4) ^ swz)) =
            (unsigned int)f2bf(a0l) | ((unsigned int)f2bf(a0h) << 16);
        *(unsigned int*)(rp + ((512 + lane * 4) ^ swz)) =
            (unsigned int)f2bf(a1l) | ((unsigned int)f2bf(a1h) << 16);
        *(unsigned int*)(rp + ((768 + lane * 4) ^ swz)) =
            (unsigned int)f2bf(a2l) | ((unsigned int)f2bf(a2h) << 16);
        *(unsigned int*)(rp + ((1024 + lane * 4) ^ swz)) =
            (unsigned int)f2bf(a3l) | ((unsigned int)f2bf(a3h) << 16);
    }
    __syncthreads();

    // Phase 2: rows 0..31 of LDS tile, wave wv covers cols [wv*32, wv*32+32)
    int n16 = lane & 15;
    int quad = lane >> 4;
    f32x4 acc[2][2];
#pragma unroll
    for (int rt = 0; rt < 2; ++rt)
#pragma unroll
        for (int c = 0; c < 2; ++c) acc[rt][c] = (f32x4)0.f;

    const char* a0p = (const char*)S + n16 * 1280;
    const char* a1p = (const char*)S + (16 + n16) * 1280;
    int swz2 = (n16 & 7) << 4;
    const unsigned short* bp = wt3 + (size_t)(wv * 2) * 512 + lane * 8;

#pragma unroll
    for (int ks = 0; ks < 20; ++ks) {
        int off = (ks * 64 + quad * 16) ^ swz2;
        bf16x8 a0 = *(const bf16x8*)(a0p + off);
        bf16x8 a1 = *(const bf16x8*)(a1p + off);
        bf16x8 b0 = *(const bf16x8*)(bp + (size_t)ks * 4096);
        bf16x8 b1 = *(const bf16x8*)(bp + (size_t)ks * 4096 + 512);
        acc[0][0] = __builtin_amdgcn_mfma_f32_16x16x32_bf16(a0, b0, acc[0][0], 0, 0, 0);
        acc[1][0] = __builtin_amdgcn_mfma_f32_16x16x32_bf16(a1, b0, acc[1][0], 0, 0, 0);
        acc[0][1] = __builtin_amdgcn_mfma_f32_16x16x32_bf16(a0, b1, acc[0][1], 0, 0, 0);
        acc[1][1] = __builtin_amdgcn_mfma_f32_16x16x32_bf16(a1, b1, acc[1][1], 0, 0, 0);
    }

    // C/D layout: col = lane&15, row = quad*4 + reg
#pragma unroll
    for (int rt = 0; rt < 2; ++rt) {
#pragma unroll
        for (int c = 0; c < 2; ++c) {
            int col = (wv * 2 + c) * 16 + n16;
            float bv = bias[col];
#pragma unroll
            for (int rg = 0; rg < 4; ++rg) {
                int r = nbase + rt * 16 + quad * 4 + rg;
                if (r < N_NODES)
                    out[(size_t)r * H_DIM + col] = fmaxf(acc[rt][c][rg] + bv, 0.f);
            }
        }
    }
}

extern "C" void kernel_launch(void* const* d_in, const int* in_sizes, int n_in,
                              void* d_out, int out_size, void* d_ws, size_t ws_size,
                              hipStream_t stream) {
    const float* h       = (const float*)d_in[0];
    const float* norm    = (const float*)d_in[1];
    const float* basis_w = (const float*)d_in[2];
    const float* w_comp  = (const float*)d_in[3];
    const float* loop_w  = (const float*)d_in[4];
    const float* bias    = (const float*)d_in[5];
    const int*   src     = (const int*)d_in[6];
    const int*   dst     = (const int*)d_in[7];
    const int*   etype   = (const int*)d_in[8];
    float* out = (float*)d_out;

    // ws layout (bytes):
    char* base = (char*)d_ws;
    unsigned short* wt3       = (unsigned short*)(base + 0);          //    163,840
    unsigned short* A         = (unsigned short*)(base + 163840);     // 12,800,000
    int*            offs      = (int*)(base + 12963840);              //    200,004
    uint2*          pkd       = (uint2*)(base + 13163848);            //  6,400,000
    uint2*          bucketed  = (uint2*)(base + 19563848);            //  6,400,000
    uint2*          sorted_pe = (uint2*)(base + 25963848);            //  6,400,000
    int*            gcnt      = (int*)(base + 32363848);              //    156,800
    int*            blkbase   = (int*)(base + 32520648);              //    156,800
    int*            btot      = (int*)(base + 32677448);              //        784
    // total ~32.7 MB

    prep_kernel<<<3330, 256, 0, stream>>>(h, basis_w, loop_w,
                                          src, dst, etype, norm,
                                          A, wt3, pkd, gcnt);
    bucket_scan_a<<<N_RANGES, 256, 0, stream>>>(gcnt, blkbase, btot);
    binscatter<<<EP_BLOCKS, 256, 0, stream>>>(pkd, blkbase, btot, bucketed);
    bucket_sort<<<N_RANGES, 256, 0, stream>>>(btot, bucketed, sorted_pe, offs);
    agg_gemm<<<1563, 256, 0, stream>>>(offs, sorted_pe, w_comp, A, wt3, bias, out);
}

// Round 2
// 172.382 us; speedup vs baseline: 1.1553x; 1.1212x over previous
//
#include <hip/hip_runtime.h>
#include <stdint.h>

#define N_NODES 50000
#define N_EDGES 800000
#define H_DIM 128
#define N_REL 40
#define N_BASES 4
#define N_RANGES 196         // node ranges of 256 (dst >> 8)
#define EP_BLOCKS 200        // edge chunks of 4000
#define EDGES_PER_BLK 4000
#define STAGE_CAP 5120       // LDS staging capacity for bucket_sort

typedef __attribute__((ext_vector_type(8))) short bf16x8;
typedef __attribute__((ext_vector_type(4))) float f32x4;

// round-to-nearest-even f32 -> bf16 bits
__device__ __forceinline__ unsigned short f2bf(float f) {
    unsigned int u = __float_as_uint(f);
    unsigned int r = u + 0x7fffu + ((u >> 16) & 1u);
    return (unsigned short)(r >> 16);
}

// ---------------------------------------------------------------------------
// K0 "prep" (fused): blocks 0..3124   -> cast h into A (bf16, stride 128)
//                    blocks 3125..3129 -> repack weights into frag-major wt3
//                    blocks 3130..3329 -> edge pack (pkd) + per-(bucket,block)
//                                         histogram (LDS only, no dev atomics)
// pkd[e] = { src | etype<<20 , dst | nbf<<17 }  (nbf = bf16 of norm >= 0)
__global__ __launch_bounds__(256) void prep_kernel(
        const float* __restrict__ h,
        const float* __restrict__ basis_w, const float* __restrict__ loop_w,
        const int* __restrict__ src, const int* __restrict__ dst,
        const int* __restrict__ etype, const float* __restrict__ norm,
        unsigned short* __restrict__ A, unsigned short* __restrict__ wt3,
        uint2* __restrict__ pkd, int* __restrict__ gcnt) {
    int bid = blockIdx.x;
    if (bid < 3125) {
        int t = bid * 256 + threadIdx.x;        // [0, 800000)
        int row = t >> 4;
        int cb = (t & 15) * 8;
        const float* p = h + (size_t)row * 128 + cb;
        float4 a0 = ((const float4*)p)[0];
        float4 a1 = ((const float4*)p)[1];
        bf16x8 o;
        o[0] = (short)f2bf(a0.x); o[1] = (short)f2bf(a0.y);
        o[2] = (short)f2bf(a0.z); o[3] = (short)f2bf(a0.w);
        o[4] = (short)f2bf(a1.x); o[5] = (short)f2bf(a1.y);
        o[6] = (short)f2bf(a1.z); o[7] = (short)f2bf(a1.w);
        *(bf16x8*)(A + (size_t)row * H_DIM + cb) = o;
    } else if (bid < 3130) {
        int mat = bid - 3125;                   // 0..3 basis, 4 loop
        const float* srcm = (mat < 4) ? (basis_w + mat * 16384) : loop_w;
        int koff = (mat < 4) ? (128 + mat * 128) : 0;
        int t = threadIdx.x;
#pragma unroll
        for (int i = 0; i < 16; ++i) {
            int f = t + i * 256;                // [0,4096) float4 index
            int k = f >> 5;
            int j4 = (f & 31) * 4;
            float4 v = ((const float4*)srcm)[f];
            int kg = koff + k;
            int ks = kg >> 5;
            int quad = (kg >> 3) & 3;
            int jj = kg & 7;
            float vv[4] = {v.x, v.y, v.z, v.w};
#pragma unroll
            for (int d = 0; d < 4; ++d) {
                int j = j4 + d;
                int cg = j >> 4;
                int n16 = j & 15;
                wt3[(size_t)((ks * 8 + cg) * 64 + quad * 16 + n16) * 8 + jj] =
                    f2bf(vv[d]);
            }
        }
    } else {
        __shared__ int lhist[N_RANGES];
        int blk = bid - 3130;                   // 0..199
        int t = threadIdx.x;
        if (t < N_RANGES) lhist[t] = 0;
        __syncthreads();
        int e0 = blk * EDGES_PER_BLK;
        for (int i = t; i < EDGES_PER_BLK; i += 256) {
            int e = e0 + i;
            int d = dst[e];
            unsigned int nbf = f2bf(norm[e]);   // <= 0x7FFF (norm >= 0)
            pkd[e] = make_uint2((unsigned)src[e] | ((unsigned)etype[e] << 20),
                                (unsigned)d | (nbf << 17));
            atomicAdd(&lhist[d >> 8], 1);
        }
        __syncthreads();
        if (t < N_RANGES) gcnt[t * EP_BLOCKS + blk] = lhist[t];
    }
}

// K1: parallel per-bucket row scan. Block r: LDS-scan gcnt[r][0..199] ->
// RELATIVE blkbase + bucket total btot[r]. Block 0 also zeroes the 16-entry
// pad past N_EDGES in sorted_src/sorted_cf (masked-batch over-read safety).
__global__ __launch_bounds__(256) void bucket_scan_a(
        const int* __restrict__ gcnt, int* __restrict__ blkbase,
        int* __restrict__ btot, unsigned* __restrict__ sorted_src,
        float4* __restrict__ sorted_cf) {
    __shared__ int wsum[4];
    int r = blockIdx.x;
    int t = threadIdx.x, lane = t & 63, w = t >> 6;
    if (r == 0 && t < 16) {
        sorted_src[N_EDGES + t] = 0u;
        sorted_cf[N_EDGES + t] = make_float4(0.f, 0.f, 0.f, 0.f);
    }
    int x = (t < EP_BLOCKS) ? gcnt[r * EP_BLOCKS + t] : 0;
    int v = x;
#pragma unroll
    for (int d = 1; d < 64; d <<= 1) {
        int y = __shfl_up(v, d);
        if (lane >= d) v += y;
    }
    if (lane == 63) wsum[w] = v;
    __syncthreads();
    int wpre = 0;
    if (w > 0) wpre += wsum[0];
    if (w > 1) wpre += wsum[1];
    if (w > 2) wpre += wsum[2];
    if (t < EP_BLOCKS) blkbase[r * EP_BLOCKS + t] = wpre + v - x;
    if (t == 255) btot[r] = wpre + v;
}

// K2: binscatter. Block b places its 4000 edges into bucket-grouped order.
// Bucket bases recomputed in-block via a 196-wide scan of btot.
__global__ __launch_bounds__(256) void binscatter(
        const uint2* __restrict__ pkd, const int* __restrict__ blkbase,
        const int* __restrict__ btot, uint2* __restrict__ bucketed) {
    __shared__ int lcur[N_RANGES];
    __shared__ int wsum[4];
    int t = threadIdx.x, lane = t & 63, w = t >> 6;
    int x = (t < N_RANGES) ? btot[t] : 0;
    int v = x;
#pragma unroll
    for (int d = 1; d < 64; d <<= 1) {
        int y = __shfl_up(v, d);
        if (lane >= d) v += y;
    }
    if (lane == 63) wsum[w] = v;
    __syncthreads();
    int wpre = 0;
    if (w > 0) wpre += wsum[0];
    if (w > 1) wpre += wsum[1];
    if (w > 2) wpre += wsum[2];
    if (t < N_RANGES)
        lcur[t] = (wpre + v - x) + blkbase[t * EP_BLOCKS + blockIdx.x];
    __syncthreads();
    int e0 = blockIdx.x * EDGES_PER_BLK;
    for (int i = t; i < EDGES_PER_BLK; i += 256) {
        uint2 p = pkd[e0 + i];
        int r = (p.y & 0x1FFFF) >> 8;
        int pos = atomicAdd(&lcur[r], 1);
        bucketed[pos] = p;
    }
}

// K3: bucket_sort. One block per bucket; base recomputed in-block.
// Pass 1: LDS per-dst histogram -> scan -> per-dst offsets (offs[] coalesced).
// Pass 2: place edges into LDS stage by exact sorted position, then stream out
// coalesced as TWO arrays: sorted_src (pure src u32) and sorted_cf
// (float4 cf = w_comp[etype]*norm, precomputed so agg does no per-edge
// w_comp load and no lane-redundant muls). f32 math identical to before.
__global__ __launch_bounds__(256) void bucket_sort(
        const int* __restrict__ btot, const uint2* __restrict__ bucketed,
        const float* __restrict__ w_comp,
        unsigned* __restrict__ sorted_src, float4* __restrict__ sorted_cf,
        int* __restrict__ offs) {
    __shared__ int hist[256];
    __shared__ int cur[256];
    __shared__ int wsum[4];
    __shared__ int sbeg;
    __shared__ uint2 stage[STAGE_CAP];
    int r = blockIdx.x;
    int t = threadIdx.x, lane = t & 63, w = t >> 6;
    // recompute begin = exclusive prefix of btot at r
    int x = (t < N_RANGES) ? btot[t] : 0;
    int v = x;
#pragma unroll
    for (int d = 1; d < 64; d <<= 1) {
        int y = __shfl_up(v, d);
        if (lane >= d) v += y;
    }
    if (lane == 63) wsum[w] = v;
    hist[t] = 0;
    __syncthreads();
    int wpre = 0;
    if (w > 0) wpre += wsum[0];
    if (w > 1) wpre += wsum[1];
    if (w > 2) wpre += wsum[2];
    if (t == r) sbeg = wpre + v - x;
    __syncthreads();
    int begin = sbeg;
    int end = begin + btot[r];
    int n = end - begin;
    for (int i = begin + t; i < end; i += 256)
        atomicAdd(&hist[bucketed[i].y & 255], 1);
    __syncthreads();
    int x2 = hist[t];
    int v2 = x2;
#pragma unroll
    for (int d = 1; d < 64; d <<= 1) {
        int y = __shfl_up(v2, d);
        if (lane >= d) v2 += y;
    }
    if (lane == 63) wsum[w] = v2;
    __syncthreads();
    int wpre2 = 0;
    if (w > 0) wpre2 += wsum[0];
    if (w > 1) wpre2 += wsum[1];
    if (w > 2) wpre2 += wsum[2];
    int excl_rel = wpre2 + v2 - x2;             // position within the region
    int node = r * 256 + t;
    if (node < N_NODES) offs[node] = begin + excl_rel;
    if (r == N_RANGES - 1 && t == 0) offs[N_NODES] = N_EDGES;
    cur[t] = excl_rel;
    __syncthreads();
    if (n <= STAGE_CAP) {
        for (int i = begin + t; i < end; i += 256) {
            uint2 p = bucketed[i];
            int pos = atomicAdd(&cur[p.y & 255], 1);
            stage[pos] = make_uint2(p.x, (p.y >> 17) << 16);
        }
        __syncthreads();
        for (int i = t; i < n; i += 256) {
            uint2 p = stage[i];
            float nm = __uint_as_float(p.y);
            float4 wc = ((const float4*)w_comp)[p.x >> 20];
            sorted_src[begin + i] = p.x & 0xFFFFF;
            sorted_cf[begin + i] =
                make_float4(wc.x * nm, wc.y * nm, wc.z * nm, wc.w * nm);
        }
    } else {                                    // pathological fallback
        for (int i = begin + t; i < end; i += 256) {
            uint2 p = bucketed[i];
            int pos = atomicAdd(&cur[p.y & 255], 1);
            float nm = __uint_as_float((p.y >> 17) << 16);
            float4 wc = ((const float4*)w_comp)[p.x >> 20];
            sorted_src[begin + pos] = p.x & 0xFFFFF;
            sorted_cf[begin + pos] =
                make_float4(wc.x * nm, wc.y * nm, wc.z * nm, wc.w * nm);
        }
    }
}

// K4 (fused aggregate + GEMM), 512 threads / 8 waves, 32-node tile:
// Phase 1: wave w aggregates nodes [32*blk + 4w, +4). Edge metadata comes
//   from sorted_src (u32) + sorted_cf (float4, precomputed w_comp*norm) —
//   wave-uniform -> s_load batches of 8; gathers are 256B bf16 rows, 8
//   outstanding. Remainder handled by a MASKED full batch (cf=0, src=0;
//   arrays are 16-entry zero-padded) — no serial dependent tail.
//   Node's 512-wide f32 S -> bf16 -> LDS tile [32][640] (with own hbf row),
//   rows XOR-swizzled (byte ^= (row&7)<<4) for bank-uniform ds_read_b128.
// Phase 2: 32x128x640 bf16 MFMA from LDS; wave = 16 cols (acc[2][1], 8
//   VGPRs), bias+relu epilogue.
// Occupancy: 4 blocks/CU (LDS 40KB*4=160KB, threads 2048) = 32 waves/CU,
// launch_bounds(512,8) caps VGPR at 64 to keep 8 waves/SIMD resident.
__global__ __launch_bounds__(512, 8) void agg_gemm(
        const int* __restrict__ offs, const unsigned* __restrict__ ssrc,
        const float4* __restrict__ scf,
        const unsigned short* __restrict__ Ab,
        const unsigned short* __restrict__ wt3,
        const float* __restrict__ bias, float* __restrict__ out) {
    __shared__ __align__(16) unsigned short S[32 * 640];   // 40 KB
    int wv = threadIdx.x >> 6;
    int lane = threadIdx.x & 63;
    int nbase = blockIdx.x * 32;
    const unsigned int* Au = (const unsigned int*)Ab;

#pragma unroll
    for (int q = 0; q < 4; ++q) {
        int row = (wv << 2) + q;
        int v = __builtin_amdgcn_readfirstlane(nbase + row);
        float a0l = 0.f, a0h = 0.f, a1l = 0.f, a1h = 0.f;
        float a2l = 0.f, a2h = 0.f, a3l = 0.f, a3h = 0.f;
        unsigned int hb = 0u;
        if (v < N_NODES) {
            hb = Au[(size_t)v * 64 + lane];     // own hbf row (cols 2l,2l+1)
            int begin = __builtin_amdgcn_readfirstlane(offs[v]);
            int end   = __builtin_amdgcn_readfirstlane(offs[v + 1]);
            for (int j = begin; j < end; j += 8) {
                int rem = end - j;              // uniform
                unsigned su[8];
                float4 c[8];
#pragma unroll
                for (int k = 0; k < 8; ++k) su[k] = ssrc[j + k];
#pragma unroll
                for (int k = 0; k < 8; ++k) c[k] = scf[j + k];
                if (rem < 8) {                  // uniform masked tail batch
#pragma unroll
                    for (int k = 0; k < 8; ++k)
                        if (k >= rem) {
                            su[k] = 0u;
                            c[k] = make_float4(0.f, 0.f, 0.f, 0.f);
                        }
                }
                unsigned u[8];
#pragma unroll
                for (int k = 0; k < 8; ++k)
                    u[k] = Au[(size_t)su[k] * 64 + lane];
#pragma unroll
                for (int k = 0; k < 8; ++k) {
                    float lo = __uint_as_float(u[k] << 16);
                    float hi = __uint_as_float(u[k] & 0xffff0000u);
                    a0l += c[k].x * lo; a0h += c[k].x * hi;
                    a1l += c[k].y * lo; a1h += c[k].y * hi;
                    a2l += c[k].z * lo; a2h += c[k].z * hi;
                    a3l += c[k].w * lo; a3h += c[k].w * hi;
                }
            }
        }
        // stage row into LDS: [hbf(256B) | S0 | S1 | S2 | S3], swizzled
        char* rp = (char*)S + row * 1280;
        int swz = (row & 7) << 4;
        *(unsigned int*)(rp + ((lane * 4) ^ swz)) = hb;
        *(unsigned int*)(rp + ((256 + lane * 4) ^ swz)) =
            (unsigned int)f2bf(a0l) | ((unsigned int)f2bf(a0h) << 16);
        *(unsigned int*)(rp + ((512 + lane * 4) ^ swz)) =
            (unsigned int)f2bf(a1l) | ((unsigned int)f2bf(a1h) << 16);
        *(unsigned int*)(rp + ((768 + lane * 4) ^ swz)) =
            (unsigned int)f2bf(a2l) | ((unsigned int)f2bf(a2h) << 16);
        *(unsigned int*)(rp + ((1024 + lane * 4) ^ swz)) =
            (unsigned int)f2bf(a3l) | ((unsigned int)f2bf(a3h) << 16);
    }
    __syncthreads();

    // Phase 2: rows 0..31 of LDS tile, wave wv covers cols [wv*16, wv*16+16)
    int n16 = lane & 15;
    int quad = lane >> 4;
    f32x4 acc0 = (f32x4)0.f, acc1 = (f32x4)0.f;

    const char* s0p = (const char*)S + n16 * 1280;
    const char* s1p = s0p + 16 * 1280;
    int swz2 = (n16 & 7) << 4;
    const unsigned short* bwp = wt3 + (size_t)wv * 512 + (size_t)lane * 8;

#pragma unroll
    for (int ks = 0; ks < 20; ++ks) {
        int off = (ks * 64 + quad * 16) ^ swz2;
        bf16x8 a0 = *(const bf16x8*)(s0p + off);
        bf16x8 a1 = *(const bf16x8*)(s1p + off);
        bf16x8 b  = *(const bf16x8*)(bwp + (size_t)ks * 4096);
        acc0 = __builtin_amdgcn_mfma_f32_16x16x32_bf16(a0, b, acc0, 0, 0, 0);
        acc1 = __builtin_amdgcn_mfma_f32_16x16x32_bf16(a1, b, acc1, 0, 0, 0);
    }

    // C/D layout: col = lane&15, row = quad*4 + reg
    int col = (wv << 4) + n16;
    float bv = bias[col];
#pragma unroll
    for (int rg = 0; rg < 4; ++rg) {
        int r0 = nbase + quad * 4 + rg;
        if (r0 < N_NODES)
            out[(size_t)r0 * H_DIM + col] = fmaxf(acc0[rg] + bv, 0.f);
        int r1 = nbase + 16 + quad * 4 + rg;
        if (r1 < N_NODES)
            out[(size_t)r1 * H_DIM + col] = fmaxf(acc1[rg] + bv, 0.f);
    }
}

extern "C" void kernel_launch(void* const* d_in, const int* in_sizes, int n_in,
                              void* d_out, int out_size, void* d_ws, size_t ws_size,
                              hipStream_t stream) {
    const float* h       = (const float*)d_in[0];
    const float* norm    = (const float*)d_in[1];
    const float* basis_w = (const float*)d_in[2];
    const float* w_comp  = (const float*)d_in[3];
    const float* loop_w  = (const float*)d_in[4];
    const float* bias    = (const float*)d_in[5];
    const int*   src     = (const int*)d_in[6];
    const int*   dst     = (const int*)d_in[7];
    const int*   etype   = (const int*)d_in[8];
    float* out = (float*)d_out;

    // ws layout (bytes):
    char* base = (char*)d_ws;
    unsigned short* wt3       = (unsigned short*)(base + 0);          //    163,840
    unsigned short* A         = (unsigned short*)(base + 163840);     // 12,800,000
    int*            offs      = (int*)(base + 12963840);              //    200,004
    uint2*          pkd       = (uint2*)(base + 13163848);            //  6,400,000
    uint2*          bucketed  = (uint2*)(base + 19563848);            //  6,400,000
    float4*         sorted_cf = (float4*)(base + 25963856);           // 12,800,256
    unsigned*       sorted_src= (unsigned*)(base + 38764112);         //  3,200,064
    int*            gcnt      = (int*)(base + 41964176);              //    156,800
    int*            blkbase   = (int*)(base + 42120976);              //    156,800
    int*            btot      = (int*)(base + 42277776);              //        784
    // total ~42.3 MB

    prep_kernel<<<3330, 256, 0, stream>>>(h, basis_w, loop_w,
                                          src, dst, etype, norm,
                                          A, wt3, pkd, gcnt);
    bucket_scan_a<<<N_RANGES, 256, 0, stream>>>(gcnt, blkbase, btot,
                                                sorted_src, sorted_cf);
    binscatter<<<EP_BLOCKS, 256, 0, stream>>>(pkd, blkbase, btot, bucketed);
    bucket_sort<<<N_RANGES, 256, 0, stream>>>(btot, bucketed, w_comp,
                                              sorted_src, sorted_cf, offs);
    agg_gemm<<<1563, 512, 0, stream>>>(offs, sorted_src, sorted_cf,
                                       A, wt3, bias, out);
}